// Round 1
// baseline (208.239 us; speedup 1.0000x reference)
//
#include <hip/hip_runtime.h>
#include <hip/hip_bf16.h>

#define DIMD 512
#define NSEQ 4096
#define LPAD 4104
#define CHUNK 513

// ws layout (float offsets); total 9,734,176 floats = 38.9 MB
#define OFF_P      0u          // 4*256*512 = 524288
#define OFF_CONST  524288u     // 512
#define OFF_Y      524800u     // 4*4104*512 = 8404992
#define OFF_T      8929792u    // 4*4104 = 16416
#define OFF_S      8946208u    // 4*4104*4 = 65664
#define OFF_S2     9011872u    // 4*4104*4 = 65664
#define OFF_ZP     9077536u    // 4*4104*8 = 131328
#define OFF_ACCP   9208864u    // 4*4104*8*4 = 525312

// ---------------------------------------------------------------------------
// K1: P[k*256+v][e] = sum_d pw_w[e,d] * emb[v,d] * dw_w[d,k]
// Tiled f32 GEMM: M=1024 (k,v), N=512 (e), K=512 (d). 64x64 tiles, BK=16.
// ---------------------------------------------------------------------------
__global__ __launch_bounds__(256) void k_ptable(
    const float* __restrict__ emb, const float* __restrict__ dw_w,
    const float* __restrict__ pw_w, float* __restrict__ P) {
  __shared__ float As[16][65];
  __shared__ float Bs[16][65];
  const int tid = threadIdx.x;
  const int m0 = blockIdx.x * 64;   // over M=1024
  const int e0 = blockIdx.y * 64;   // over N=512
  const int tx = tid & 15, ty = tid >> 4;
  float c[4][4] = {};
  const int row = tid >> 2;         // 0..63
  const int dd  = (tid & 3) << 2;   // 0,4,8,12
  const int m = m0 + row;
  const int kk = m >> 8;            // conv tap 0..3
  const int v = m & 255;            // vocab id
  const int e = e0 + row;
  for (int d0 = 0; d0 < DIMD; d0 += 16) {
    const int d = d0 + dd;
    float4 ev = *reinterpret_cast<const float4*>(&emb[v * DIMD + d]);
    As[dd + 0][row] = ev.x * dw_w[(d + 0) * 4 + kk];
    As[dd + 1][row] = ev.y * dw_w[(d + 1) * 4 + kk];
    As[dd + 2][row] = ev.z * dw_w[(d + 2) * 4 + kk];
    As[dd + 3][row] = ev.w * dw_w[(d + 3) * 4 + kk];
    float4 bv = *reinterpret_cast<const float4*>(&pw_w[e * DIMD + d]);
    Bs[dd + 0][row] = bv.x;
    Bs[dd + 1][row] = bv.y;
    Bs[dd + 2][row] = bv.z;
    Bs[dd + 3][row] = bv.w;
    __syncthreads();
    #pragma unroll
    for (int q = 0; q < 16; ++q) {
      float a0 = As[q][ty * 4 + 0], a1 = As[q][ty * 4 + 1];
      float a2 = As[q][ty * 4 + 2], a3 = As[q][ty * 4 + 3];
      float b0 = Bs[q][tx * 4 + 0], b1 = Bs[q][tx * 4 + 1];
      float b2 = Bs[q][tx * 4 + 2], b3 = Bs[q][tx * 4 + 3];
      c[0][0] += a0 * b0; c[0][1] += a0 * b1; c[0][2] += a0 * b2; c[0][3] += a0 * b3;
      c[1][0] += a1 * b0; c[1][1] += a1 * b1; c[1][2] += a1 * b2; c[1][3] += a1 * b3;
      c[2][0] += a2 * b0; c[2][1] += a2 * b1; c[2][2] += a2 * b2; c[2][3] += a2 * b3;
      c[3][0] += a3 * b0; c[3][1] += a3 * b1; c[3][2] += a3 * b2; c[3][3] += a3 * b3;
    }
    __syncthreads();
  }
  for (int i = 0; i < 4; ++i) {
    int mm = m0 + ty * 4 + i;
    float4 o = make_float4(c[i][0], c[i][1], c[i][2], c[i][3]);
    *reinterpret_cast<float4*>(&P[mm * DIMD + e0 + tx * 4]) = o;
  }
}

// ---------------------------------------------------------------------------
// K1b: constv[e] = pw_b[e] + sum_d pw_w[e,d]*dw_b[d]   (dw_b is zeros here,
// but keep general)
// ---------------------------------------------------------------------------
__global__ __launch_bounds__(256) void k_const(
    const float* __restrict__ pw_w, const float* __restrict__ pw_b,
    const float* __restrict__ dw_b, float* __restrict__ constv) {
  const int e = blockIdx.x * 256 + threadIdx.x;
  float acc = pw_b[e];
  for (int d = 0; d < DIMD; ++d) acc += pw_w[e * DIMD + d] * dw_b[d];
  constv[e] = acc;
}

// ---------------------------------------------------------------------------
// K2: y[b,i,e] = sum_{k, i+k<NSEQ} P[k][x[b,i+k]][e] + constv[e]  (i<NSEQ)
//     y[b,i,e] = 0 for i in [NSEQ, LPAD)
// ---------------------------------------------------------------------------
__global__ __launch_bounds__(128) void k_y(
    const int* __restrict__ x, const float* __restrict__ P,
    const float* __restrict__ constv, float* __restrict__ y) {
  const int b = blockIdx.y;
  const int i0 = blockIdx.x * 8;
  const int t = threadIdx.x;  // 0..127, owns float4 at e = t*4
  float4 cv = *reinterpret_cast<const float4*>(&constv[t * 4]);
  for (int r = 0; r < 8; ++r) {
    int i = i0 + r;
    float ax = 0.f, ay = 0.f, az = 0.f, aw = 0.f;
    if (i < NSEQ) {
      ax = cv.x; ay = cv.y; az = cv.z; aw = cv.w;
      #pragma unroll
      for (int k = 0; k < 4; ++k) {
        int pos = i + k;
        if (pos < NSEQ) {
          int tok = x[b * NSEQ + pos];
          const float4 pv = *reinterpret_cast<const float4*>(
              &P[((unsigned)(k << 8) + tok) * DIMD + t * 4]);
          ax += pv.x; ay += pv.y; az += pv.z; aw += pv.w;
        }
      }
    }
    *reinterpret_cast<float4*>(&y[((size_t)(b * LPAD) + i) * DIMD + t * 4]) =
        make_float4(ax, ay, az, aw);
  }
}

// ---------------------------------------------------------------------------
// K3: t[b,j] = dot(y[b,j,:], score_w)   (one wave per row)
// ---------------------------------------------------------------------------
__global__ __launch_bounds__(256) void k_t(
    const float* __restrict__ y, const float* __restrict__ score_w,
    float* __restrict__ t_out) {
  const int b = blockIdx.y;
  const int w = threadIdx.x >> 6;
  const int lane = threadIdx.x & 63;
  const int row = blockIdx.x * 4 + w;  // 1026*4 = 4104 exact
  const float* yr = &y[((size_t)(b * LPAD) + row) * DIMD];
  float4 y0 = *reinterpret_cast<const float4*>(&yr[lane * 4]);
  float4 y1 = *reinterpret_cast<const float4*>(&yr[256 + lane * 4]);
  float4 w0 = *reinterpret_cast<const float4*>(&score_w[lane * 4]);
  float4 w1 = *reinterpret_cast<const float4*>(&score_w[256 + lane * 4]);
  float p = y0.x * w0.x + y0.y * w0.y + y0.z * w0.z + y0.w * w0.w
          + y1.x * w1.x + y1.y * w1.y + y1.z * w1.z + y1.w * w1.w;
  for (int off = 32; off > 0; off >>= 1) p += __shfl_down(p, off);
  if (lane == 0) t_out[b * LPAD + row] = p;
}

// ---------------------------------------------------------------------------
// K4: s[b,l,:] = softmax_k( blockmean_k(t) + score_b )
// ---------------------------------------------------------------------------
__global__ __launch_bounds__(256) void k_s(
    const float* __restrict__ t_in, const float* __restrict__ score_b_p,
    float* __restrict__ s) {
  const int b = blockIdx.y;
  const int l = blockIdx.x * 256 + threadIdx.x;
  if (l >= LPAD) return;
  const float* tb = &t_in[b * LPAD];
  const float sb = score_b_p[0];
  float p0 = tb[l] + sb;
  int j2 = l & ~1;
  float p1 = (tb[j2] + tb[j2 + 1]) * 0.5f + sb;
  int j3 = (l / 3) * 3;
  float p2 = (tb[j3] + tb[j3 + 1] + tb[j3 + 2]) * (1.0f / 3.0f) + sb;
  int j4 = l & ~3;
  float p3 = (tb[j4] + tb[j4 + 1] + tb[j4 + 2] + tb[j4 + 3]) * 0.25f + sb;
  float mx = fmaxf(fmaxf(p0, p1), fmaxf(p2, p3));
  float e0 = __expf(p0 - mx), e1 = __expf(p1 - mx);
  float e2 = __expf(p2 - mx), e3 = __expf(p3 - mx);
  float inv = 1.0f / (e0 + e1 + e2 + e3);
  *reinterpret_cast<float4*>(&s[((size_t)(b * LPAD) + l) * 4]) =
      make_float4(e0 * inv, e1 * inv, e2 * inv, e3 * inv);
}

// ---------------------------------------------------------------------------
// K5: streaming attention partials over j-chunks.
// sim in [0,1] => exp never overflows => no max tracking needed (same ratio
// as reference's stabilized softmax).
// ---------------------------------------------------------------------------
__global__ __launch_bounds__(64) void k_attn(
    const float* __restrict__ s, float* __restrict__ Zp,
    float* __restrict__ accp) {
  const int b = blockIdx.z;
  const int c = blockIdx.y;
  const int i = blockIdx.x * 64 + threadIdx.x;
  __shared__ float4 sch[CHUNK];
  const float4* s4 = reinterpret_cast<const float4*>(s) + (size_t)b * LPAD;
  const int j0 = c * CHUNK;
  for (int idx = threadIdx.x; idx < CHUNK; idx += 64) sch[idx] = s4[j0 + idx];
  __syncthreads();
  if (i >= LPAD) return;
  float4 si = s4[i];
  float z0 = 0.f, z1 = 0.f;
  float a0x = 0.f, a0y = 0.f, a0z = 0.f, a0w = 0.f;
  float a1x = 0.f, a1y = 0.f, a1z = 0.f, a1w = 0.f;
  #pragma unroll 4
  for (int jj = 0; jj < CHUNK - 1; jj += 2) {
    float4 u = sch[jj];
    float4 v = sch[jj + 1];
    float d0 = si.x * u.x + si.y * u.y + si.z * u.z + si.w * u.w;
    float d1 = si.x * v.x + si.y * v.y + si.z * v.z + si.w * v.w;
    float e0 = __expf(d0), e1 = __expf(d1);
    z0 += e0; a0x += e0 * u.x; a0y += e0 * u.y; a0z += e0 * u.z; a0w += e0 * u.w;
    z1 += e1; a1x += e1 * v.x; a1y += e1 * v.y; a1z += e1 * v.z; a1w += e1 * v.w;
  }
  {  // tail (CHUNK odd)
    float4 u = sch[CHUNK - 1];
    float d0 = si.x * u.x + si.y * u.y + si.z * u.z + si.w * u.w;
    float e0 = __expf(d0);
    z0 += e0; a0x += e0 * u.x; a0y += e0 * u.y; a0z += e0 * u.z; a0w += e0 * u.w;
  }
  const size_t base = ((size_t)(b * LPAD) + i) * 8 + c;
  Zp[base] = z0 + z1;
  reinterpret_cast<float4*>(accp)[base] =
      make_float4(a0x + a1x, a0y + a1y, a0z + a1z, a0w + a1w);
}

// ---------------------------------------------------------------------------
// K6: combine chunk partials: s2[b,l,k] = (sum_c acc) / (sum_c Z)
// ---------------------------------------------------------------------------
__global__ __launch_bounds__(256) void k_comb(
    const float* __restrict__ Zp, const float* __restrict__ accp,
    float* __restrict__ s2) {
  const int b = blockIdx.y;
  const int l = blockIdx.x * 256 + threadIdx.x;
  if (l >= LPAD) return;
  const size_t base = ((size_t)(b * LPAD) + l) * 8;
  float z = 0.f, ax = 0.f, ay = 0.f, az = 0.f, aw = 0.f;
  const float4* a4 = reinterpret_cast<const float4*>(accp);
  for (int c = 0; c < 8; ++c) {
    z += Zp[base + c];
    float4 a = a4[base + c];
    ax += a.x; ay += a.y; az += a.z; aw += a.w;
  }
  float inv = 1.0f / z;
  reinterpret_cast<float4*>(s2)[(size_t)(b * LPAD) + l] =
      make_float4(ax * inv, ay * inv, az * inv, aw * inv);
}

// ---------------------------------------------------------------------------
// K7: final recombine + DS-mean. Output group g uses y rows [jbase, jbase+8).
// out[b,g,d] = sum_r coef[r] * y[b, jbase+r, d],
// coef built from s2 weights / (bs*DS).
// ---------------------------------------------------------------------------
__global__ __launch_bounds__(128) void k_out(
    const float* __restrict__ y, const float* __restrict__ s2,
    float* __restrict__ out) {
  const int b = blockIdx.y;
  const int g = blockIdx.x;
  const int tid = threadIdx.x;
  __shared__ float coef[8];
  const int jbase = (g == 0) ? 0 : 4 * g - 2;
  if (tid == 0) {
    float cf[8] = {0.f, 0.f, 0.f, 0.f, 0.f, 0.f, 0.f, 0.f};
    const float4* s2_4 = reinterpret_cast<const float4*>(s2) + (size_t)b * LPAD;
    for (int dl = 0; dl < 4; ++dl) {
      int l = 4 * g + dl;
      float4 sv = s2_4[l];
      float sk[4] = {sv.x, sv.y, sv.z, sv.w};
      for (int k = 0; k < 4; ++k) {
        int bs = k + 1;
        int j0 = (l / bs) * bs;
        float wv = sk[k] / (float)(bs * 4);
        for (int jj = 0; jj < bs; ++jj) cf[j0 + jj - jbase] += wv;
      }
    }
    for (int r = 0; r < 8; ++r) coef[r] = cf[r];
  }
  __syncthreads();
  const float4* y4 =
      reinterpret_cast<const float4*>(y) + ((size_t)(b * LPAD) + jbase) * 128;
  float ax = 0.f, ay = 0.f, az = 0.f, aw = 0.f;
  #pragma unroll
  for (int r = 0; r < 8; ++r) {
    float cr = coef[r];
    float4 v = y4[r * 128 + tid];
    ax += cr * v.x; ay += cr * v.y; az += cr * v.z; aw += cr * v.w;
  }
  reinterpret_cast<float4*>(out)[((size_t)(b * 1024) + g) * 128 + tid] =
      make_float4(ax, ay, az, aw);
}

extern "C" void kernel_launch(void* const* d_in, const int* in_sizes, int n_in,
                              void* d_out, int out_size, void* d_ws, size_t ws_size,
                              hipStream_t stream) {
  const int* x = (const int*)d_in[0];
  const float* emb = (const float*)d_in[1];
  const float* dw_w = (const float*)d_in[2];
  const float* dw_b = (const float*)d_in[3];
  const float* pw_w = (const float*)d_in[4];
  const float* pw_b = (const float*)d_in[5];
  const float* score_w = (const float*)d_in[6];
  const float* score_b = (const float*)d_in[7];
  float* out = (float*)d_out;
  float* ws = (float*)d_ws;
  float* P      = ws + OFF_P;
  float* constv = ws + OFF_CONST;
  float* y      = ws + OFF_Y;
  float* t      = ws + OFF_T;
  float* s      = ws + OFF_S;
  float* s2     = ws + OFF_S2;
  float* Zp     = ws + OFF_ZP;
  float* accp   = ws + OFF_ACCP;

  k_ptable<<<dim3(16, 8), 256, 0, stream>>>(emb, dw_w, pw_w, P);
  k_const<<<2, 256, 0, stream>>>(pw_w, pw_b, dw_b, constv);
  k_y<<<dim3(513, 4), 128, 0, stream>>>(x, P, constv, y);
  k_t<<<dim3(1026, 4), 256, 0, stream>>>(y, score_w, t);
  k_s<<<dim3(17, 4), 256, 0, stream>>>(t, score_b, s);
  k_attn<<<dim3(65, 8, 4), 64, 0, stream>>>(s, Zp, accp);
  k_comb<<<dim3(17, 4), 256, 0, stream>>>(Zp, accp, s2);
  k_out<<<dim3(1024, 4), 128, 0, stream>>>(y, s2, out);
}

// Round 3
// 166.989 us; speedup vs baseline: 1.2470x; 1.2470x over previous
//
#include <hip/hip_runtime.h>
#include <hip/hip_bf16.h>

#define DIMD 512
#define NSEQ 4096
#define LPAD 4104
#define NCH 12
#define CH 342          // 12 * 342 = 4104 exactly
#define SPLITS 8
#define PT_BK 32

// ws layout (float offsets). Aliasing is stream-order-safe:
//   P region [0,524288) is dead after k_y -> reused for ZACC/AACC (zeroed in k_s)
//   Y region is dead until k_y -> PPART (ptable split-K partials) lives there first
// Total footprint: 9,077,536 floats = 36.3 MB (<= 38.9 MB proven working).
#define OFF_P      0u          // 4*256*512 = 524288
#define OFF_ZACC   0u          // 4*4104 = 16416            (aliases P, used later)
#define OFF_AACC   16416u      // 4*4104*4 = 65664          (aliases P, used later)
#define OFF_CONST  524288u     // 512
#define OFF_Y      524800u     // 4*4104*512 = 8404992
#define OFF_PPART  524800u     // 8*1024*512 = 4194304      (aliases Y, used first)
#define OFF_T      8929792u    // 4*4104 = 16416
#define OFF_S      8946208u    // 4*4104*4 = 65664
#define OFF_S2     9011872u    // 4*4104*4 = 65664

// ---------------------------------------------------------------------------
// K1: split-K GEMM for P[k*256+v][e] = sum_d emb[v,d]*dw_w[d,k]*pw_w[e,d]
// M=1024 (k,v), N=512 (e), K=512 (d). 64x64 tiles, 8 K-splits of 64, BK=32.
// Grid (16,8,8)=1024 blocks -> ~50% occupancy vs old 6%.
// ---------------------------------------------------------------------------
__global__ __launch_bounds__(256) void k_ptable(
    const float* __restrict__ emb, const float* __restrict__ dw_w,
    const float* __restrict__ pw_w, float* __restrict__ Ppart) {
  __shared__ float As[PT_BK][68];   // [d_local][m_row]; stride 68 floats = 272B (16B-aligned)
  __shared__ float Bs[PT_BK][68];   // [d_local][e_row]
  const int tid = threadIdx.x;
  const int m0 = blockIdx.x * 64;
  const int e0 = blockIdx.y * 64;
  const int z  = blockIdx.z;
  const int kk = m0 >> 8;           // conv tap, constant per block (64 | 256)
  const int v0 = m0 & 255;
  const int srow = tid >> 3;        // 0..31
  const int sd4  = (tid & 7) * 4;   // 0,4,...,28
  const int ty = tid >> 4, tx = tid & 15;
  float c[4][4] = {};
  for (int kt = 0; kt < 64; kt += PT_BK) {
    const int d0 = z * 64 + kt;
    const float dw0 = dw_w[(d0 + sd4 + 0) * 4 + kk];
    const float dw1 = dw_w[(d0 + sd4 + 1) * 4 + kk];
    const float dw2 = dw_w[(d0 + sd4 + 2) * 4 + kk];
    const float dw3 = dw_w[(d0 + sd4 + 3) * 4 + kk];
    #pragma unroll
    for (int rr = 0; rr < 2; ++rr) {
      const int row = srow + rr * 32;
      float4 ev = *reinterpret_cast<const float4*>(&emb[(v0 + row) * DIMD + d0 + sd4]);
      As[sd4 + 0][row] = ev.x * dw0;
      As[sd4 + 1][row] = ev.y * dw1;
      As[sd4 + 2][row] = ev.z * dw2;
      As[sd4 + 3][row] = ev.w * dw3;
      float4 bv = *reinterpret_cast<const float4*>(&pw_w[(e0 + row) * DIMD + d0 + sd4]);
      Bs[sd4 + 0][row] = bv.x;
      Bs[sd4 + 1][row] = bv.y;
      Bs[sd4 + 2][row] = bv.z;
      Bs[sd4 + 3][row] = bv.w;
    }
    __syncthreads();
    #pragma unroll
    for (int q = 0; q < PT_BK; ++q) {
      float4 a = *reinterpret_cast<const float4*>(&As[q][ty * 4]);
      float4 b = *reinterpret_cast<const float4*>(&Bs[q][tx * 4]);
      c[0][0] += a.x * b.x; c[0][1] += a.x * b.y; c[0][2] += a.x * b.z; c[0][3] += a.x * b.w;
      c[1][0] += a.y * b.x; c[1][1] += a.y * b.y; c[1][2] += a.y * b.z; c[1][3] += a.y * b.w;
      c[2][0] += a.z * b.x; c[2][1] += a.z * b.y; c[2][2] += a.z * b.z; c[2][3] += a.z * b.w;
      c[3][0] += a.w * b.x; c[3][1] += a.w * b.y; c[3][2] += a.w * b.z; c[3][3] += a.w * b.w;
    }
    __syncthreads();
  }
  #pragma unroll
  for (int i = 0; i < 4; ++i) {
    *reinterpret_cast<float4*>(
        &Ppart[(size_t)z * 524288u + (m0 + ty * 4 + i) * DIMD + e0 + tx * 4]) =
        make_float4(c[i][0], c[i][1], c[i][2], c[i][3]);
  }
}

// K1c: P = sum over splits of Ppart
__global__ __launch_bounds__(256) void k_pcomb(
    const float* __restrict__ Ppart, float* __restrict__ P) {
  const int idx = blockIdx.x * 256 + threadIdx.x;  // over 131072 float4
  const float4* p4 = reinterpret_cast<const float4*>(Ppart);
  float4 a = p4[idx];
  #pragma unroll
  for (int zz = 1; zz < SPLITS; ++zz) {
    float4 v = p4[(size_t)zz * 131072u + idx];
    a.x += v.x; a.y += v.y; a.z += v.z; a.w += v.w;
  }
  reinterpret_cast<float4*>(P)[idx] = a;
}

// K1b: constv[e] = pw_b[e] + sum_d pw_w[e,d]*dw_b[d]
__global__ __launch_bounds__(256) void k_const(
    const float* __restrict__ pw_w, const float* __restrict__ pw_b,
    const float* __restrict__ dw_b, float* __restrict__ constv) {
  const int e = blockIdx.x * 256 + threadIdx.x;
  float acc = pw_b[e];
  for (int d = 0; d < DIMD; ++d) acc += pw_w[e * DIMD + d] * dw_b[d];
  constv[e] = acc;
}

// ---------------------------------------------------------------------------
// K2: y[b,i,:] = sum_k P[k][x[b,i+k]][:] + constv  (zeros for pad rows)
//     fused: t[b,i] = dot(y[b,i,:], score_w)   (eliminates a 33.6MB re-read)
// ---------------------------------------------------------------------------
__global__ __launch_bounds__(128) void k_y(
    const int* __restrict__ x, const float* __restrict__ P,
    const float* __restrict__ constv, const float* __restrict__ score_w,
    float* __restrict__ y, float* __restrict__ t_out) {
  const int b = blockIdx.y;
  const int i0 = blockIdx.x * 8;
  const int t = threadIdx.x;  // owns float4 at e = t*4
  __shared__ float red[2][8];
  float4 cv = reinterpret_cast<const float4*>(constv)[t];
  float4 sw = reinterpret_cast<const float4*>(score_w)[t];
  float td[8];
  for (int r = 0; r < 8; ++r) {
    const int i = i0 + r;
    float ax = 0.f, ay = 0.f, az = 0.f, aw = 0.f;
    if (i < NSEQ) {
      ax = cv.x; ay = cv.y; az = cv.z; aw = cv.w;
      #pragma unroll
      for (int k = 0; k < 4; ++k) {
        const int pos = i + k;
        if (pos < NSEQ) {
          const int tok = x[b * NSEQ + pos];
          const float4 pv = *reinterpret_cast<const float4*>(
              &P[((unsigned)(k << 8) + tok) * DIMD + t * 4]);
          ax += pv.x; ay += pv.y; az += pv.z; aw += pv.w;
        }
      }
    }
    *reinterpret_cast<float4*>(&y[((size_t)(b * LPAD) + i) * DIMD + t * 4]) =
        make_float4(ax, ay, az, aw);
    td[r] = ax * sw.x + ay * sw.y + az * sw.z + aw * sw.w;
  }
  const int lane = t & 63, wv = t >> 6;
  #pragma unroll
  for (int r = 0; r < 8; ++r) {
    float p = td[r];
    for (int off = 32; off > 0; off >>= 1) p += __shfl_down(p, off);
    if (lane == 0) red[wv][r] = p;
  }
  __syncthreads();
  if (t < 8) t_out[b * LPAD + i0 + t] = red[0][t] + red[1][t];
}

// ---------------------------------------------------------------------------
// K4: s[b,l,:] = softmax_k( blockmean_k(t) + score_b )
//     also zero-inits the attention accumulators (ZACC/AACC alias dead P).
// ---------------------------------------------------------------------------
__global__ __launch_bounds__(256) void k_s(
    const float* __restrict__ t_in, const float* __restrict__ score_b_p,
    float* __restrict__ s, float* __restrict__ Zacc, float* __restrict__ Aacc) {
  const int b = blockIdx.y;
  const int l = blockIdx.x * 256 + threadIdx.x;
  if (l >= LPAD) return;
  Zacc[b * LPAD + l] = 0.f;
  reinterpret_cast<float4*>(Aacc)[(size_t)(b * LPAD) + l] = make_float4(0.f, 0.f, 0.f, 0.f);
  const float* tb = &t_in[b * LPAD];
  const float sb = score_b_p[0];
  float p0 = tb[l] + sb;
  int j2 = l & ~1;
  float p1 = (tb[j2] + tb[j2 + 1]) * 0.5f + sb;
  int j3 = (l / 3) * 3;
  float p2 = (tb[j3] + tb[j3 + 1] + tb[j3 + 2]) * (1.0f / 3.0f) + sb;
  int j4 = l & ~3;
  float p3 = (tb[j4] + tb[j4 + 1] + tb[j4 + 2] + tb[j4 + 3]) * 0.25f + sb;
  float mx = fmaxf(fmaxf(p0, p1), fmaxf(p2, p3));
  float e0 = __expf(p0 - mx), e1 = __expf(p1 - mx);
  float e2 = __expf(p2 - mx), e3 = __expf(p3 - mx);
  float inv = 1.0f / (e0 + e1 + e2 + e3);
  *reinterpret_cast<float4*>(&s[((size_t)(b * LPAD) + l) * 4]) =
      make_float4(e0 * inv, e1 * inv, e2 * inv, e3 * inv);
}

// ---------------------------------------------------------------------------
// K5: streaming attention over 12 j-chunks; atomic accumulation into Z/A.
// sim in [0,1] => exp never overflows => no max tracking needed.
// ---------------------------------------------------------------------------
__global__ __launch_bounds__(64) void k_attn(
    const float* __restrict__ s, float* __restrict__ Zacc,
    float* __restrict__ Aacc) {
  const int b = blockIdx.z;
  const int c = blockIdx.y;
  const int i = blockIdx.x * 64 + threadIdx.x;
  __shared__ float4 sch[CH];
  const float4* s4 = reinterpret_cast<const float4*>(s) + (size_t)b * LPAD;
  const int j0 = c * CH;
  for (int idx = threadIdx.x; idx < CH; idx += 64) sch[idx] = s4[j0 + idx];
  __syncthreads();
  if (i >= LPAD) return;
  float4 si = s4[i];
  float z0 = 0.f, z1 = 0.f;
  float a0x = 0.f, a0y = 0.f, a0z = 0.f, a0w = 0.f;
  float a1x = 0.f, a1y = 0.f, a1z = 0.f, a1w = 0.f;
  #pragma unroll 3
  for (int jj = 0; jj < CH; jj += 2) {
    float4 u = sch[jj];
    float4 v = sch[jj + 1];
    float d0 = si.x * u.x + si.y * u.y + si.z * u.z + si.w * u.w;
    float d1 = si.x * v.x + si.y * v.y + si.z * v.z + si.w * v.w;
    float e0 = __expf(d0), e1 = __expf(d1);
    z0 += e0; a0x += e0 * u.x; a0y += e0 * u.y; a0z += e0 * u.z; a0w += e0 * u.w;
    z1 += e1; a1x += e1 * v.x; a1y += e1 * v.y; a1z += e1 * v.z; a1w += e1 * v.w;
  }
  float* za = &Zacc[b * LPAD + i];
  float* aa = &Aacc[((size_t)(b * LPAD) + i) * 4];
  atomicAdd(za, z0 + z1);
  atomicAdd(aa + 0, a0x + a1x);
  atomicAdd(aa + 1, a0y + a1y);
  atomicAdd(aa + 2, a0z + a1z);
  atomicAdd(aa + 3, a0w + a1w);
}

// K6: s2[b,l,k] = Aacc / Zacc
__global__ __launch_bounds__(256) void k_s2(
    const float* __restrict__ Zacc, const float* __restrict__ Aacc,
    float* __restrict__ s2) {
  const int b = blockIdx.y;
  const int l = blockIdx.x * 256 + threadIdx.x;
  if (l >= LPAD) return;
  const size_t idx = (size_t)(b * LPAD) + l;
  float4 a = reinterpret_cast<const float4*>(Aacc)[idx];
  float inv = 1.0f / Zacc[idx];
  reinterpret_cast<float4*>(s2)[idx] =
      make_float4(a.x * inv, a.y * inv, a.z * inv, a.w * inv);
}

// ---------------------------------------------------------------------------
// K7: final recombine + DS-mean: out[b,g,:] = sum_{r<8} coef[r]*y[b,jbase+r,:]
// ---------------------------------------------------------------------------
__global__ __launch_bounds__(128) void k_out(
    const float* __restrict__ y, const float* __restrict__ s2,
    float* __restrict__ out) {
  const int b = blockIdx.y;
  const int g = blockIdx.x;
  const int tid = threadIdx.x;
  __shared__ float coef[8];
  const int jbase = (g == 0) ? 0 : 4 * g - 2;
  if (tid == 0) {
    float cf[8] = {0.f, 0.f, 0.f, 0.f, 0.f, 0.f, 0.f, 0.f};
    const float4* s2_4 = reinterpret_cast<const float4*>(s2) + (size_t)b * LPAD;
    for (int dl = 0; dl < 4; ++dl) {
      int l = 4 * g + dl;
      float4 sv = s2_4[l];
      float sk[4] = {sv.x, sv.y, sv.z, sv.w};
      for (int k = 0; k < 4; ++k) {
        int bs = k + 1;
        int j0 = (l / bs) * bs;
        float wv = sk[k] / (float)(bs * 4);
        for (int jj = 0; jj < bs; ++jj) cf[j0 + jj - jbase] += wv;
      }
    }
    for (int r = 0; r < 8; ++r) coef[r] = cf[r];
  }
  __syncthreads();
  const float4* y4 =
      reinterpret_cast<const float4*>(y) + ((size_t)(b * LPAD) + jbase) * 128;
  float ax = 0.f, ay = 0.f, az = 0.f, aw = 0.f;
  #pragma unroll
  for (int r = 0; r < 8; ++r) {
    float cr = coef[r];
    float4 v = y4[r * 128 + tid];
    ax += cr * v.x; ay += cr * v.y; az += cr * v.z; aw += cr * v.w;
  }
  reinterpret_cast<float4*>(out)[((size_t)(b * 1024) + g) * 128 + tid] =
      make_float4(ax, ay, az, aw);
}

extern "C" void kernel_launch(void* const* d_in, const int* in_sizes, int n_in,
                              void* d_out, int out_size, void* d_ws, size_t ws_size,
                              hipStream_t stream) {
  const int* x = (const int*)d_in[0];
  const float* emb = (const float*)d_in[1];
  const float* dw_w = (const float*)d_in[2];
  const float* dw_b = (const float*)d_in[3];
  const float* pw_w = (const float*)d_in[4];
  const float* pw_b = (const float*)d_in[5];
  const float* score_w = (const float*)d_in[6];
  const float* score_b = (const float*)d_in[7];
  float* out = (float*)d_out;
  float* ws = (float*)d_ws;
  float* P      = ws + OFF_P;
  float* Zacc   = ws + OFF_ZACC;   // aliases P (P dead after k_y)
  float* Aacc   = ws + OFF_AACC;   // aliases P
  float* constv = ws + OFF_CONST;
  float* y      = ws + OFF_Y;
  float* Ppart  = ws + OFF_PPART;  // aliases y (y written after k_pcomb)
  float* t      = ws + OFF_T;
  float* s      = ws + OFF_S;
  float* s2     = ws + OFF_S2;

  k_ptable<<<dim3(16, 8, SPLITS), 256, 0, stream>>>(emb, dw_w, pw_w, Ppart);
  k_pcomb<<<512, 256, 0, stream>>>(Ppart, P);
  k_const<<<2, 256, 0, stream>>>(pw_w, pw_b, dw_b, constv);
  k_y<<<dim3(513, 4), 128, 0, stream>>>(x, P, constv, score_w, y, t);
  k_s<<<dim3(17, 4), 256, 0, stream>>>(t, score_b, s, Zacc, Aacc);
  k_attn<<<dim3(65, NCH, 4), 64, 0, stream>>>(s, Zacc, Aacc);
  k_s2<<<dim3(17, 4), 256, 0, stream>>>(Zacc, Aacc, s2);
  k_out<<<dim3(1024, 4), 128, 0, stream>>>(y, s2, out);
}

// Round 4
// 156.276 us; speedup vs baseline: 1.3325x; 1.0686x over previous
//
#include <hip/hip_runtime.h>
#include <hip/hip_bf16.h>

#define DIMD 512
#define NSEQ 4096
#define LPAD 4104
#define NCH 12
#define CH 342          // 12 * 342 = 4104 exactly
#define SPLITS 8
#define PT_BK 32

// ws layout (float offsets) — no aliasing, total 6,968,096 floats = 27.9 MB.
#define OFF_P      0u          // 4*256*512 = 524288
#define OFF_CONST  524288u     // 512
#define OFF_T      524800u     // 4*4104 = 16416
#define OFF_S      541216u     // 4*4104*4 = 65664
#define OFF_AACC   606880u     // 4*4104*4 = 65664
#define OFF_Y      672544u     // bf16: 4*4104*512 = 8404992 bf16 = 2101248 floats
#define OFF_PPART  2773792u    // 8*1024*512 = 4194304

static __device__ __forceinline__ unsigned short f2bf(float f) {
  unsigned u = __float_as_uint(f);
  unsigned r = (u + 0x7FFFu + ((u >> 16) & 1u)) >> 16;   // RNE
  return (unsigned short)r;
}
static __device__ __forceinline__ float bf2f(unsigned short h) {
  return __uint_as_float(((unsigned)h) << 16);
}

// ---------------------------------------------------------------------------
// K1: split-K GEMM for P[k*256+v][e] = sum_d emb[v,d]*dw_w[d,k]*pw_w[e,d]
// M=1024 (k,v), N=512 (e), K=512 (d). 64x64 tiles, 8 K-splits of 64, BK=32.
// ---------------------------------------------------------------------------
__global__ __launch_bounds__(256) void k_ptable(
    const float* __restrict__ emb, const float* __restrict__ dw_w,
    const float* __restrict__ pw_w, float* __restrict__ Ppart) {
  __shared__ float As[PT_BK][68];   // [d_local][m_row]
  __shared__ float Bs[PT_BK][68];   // [d_local][e_row]
  const int tid = threadIdx.x;
  const int m0 = blockIdx.x * 64;
  const int e0 = blockIdx.y * 64;
  const int z  = blockIdx.z;
  const int kk = m0 >> 8;           // conv tap, constant per block
  const int v0 = m0 & 255;
  const int srow = tid >> 3;        // 0..31
  const int sd4  = (tid & 7) * 4;   // 0..28
  const int ty = tid >> 4, tx = tid & 15;
  float c[4][4] = {};
  for (int kt = 0; kt < 64; kt += PT_BK) {
    const int d0 = z * 64 + kt;
    const float dw0 = dw_w[(d0 + sd4 + 0) * 4 + kk];
    const float dw1 = dw_w[(d0 + sd4 + 1) * 4 + kk];
    const float dw2 = dw_w[(d0 + sd4 + 2) * 4 + kk];
    const float dw3 = dw_w[(d0 + sd4 + 3) * 4 + kk];
    #pragma unroll
    for (int rr = 0; rr < 2; ++rr) {
      const int row = srow + rr * 32;
      float4 ev = *reinterpret_cast<const float4*>(&emb[(v0 + row) * DIMD + d0 + sd4]);
      As[sd4 + 0][row] = ev.x * dw0;
      As[sd4 + 1][row] = ev.y * dw1;
      As[sd4 + 2][row] = ev.z * dw2;
      As[sd4 + 3][row] = ev.w * dw3;
      float4 bv = *reinterpret_cast<const float4*>(&pw_w[(e0 + row) * DIMD + d0 + sd4]);
      Bs[sd4 + 0][row] = bv.x;
      Bs[sd4 + 1][row] = bv.y;
      Bs[sd4 + 2][row] = bv.z;
      Bs[sd4 + 3][row] = bv.w;
    }
    __syncthreads();
    #pragma unroll
    for (int q = 0; q < PT_BK; ++q) {
      float4 a = *reinterpret_cast<const float4*>(&As[q][ty * 4]);
      float4 b = *reinterpret_cast<const float4*>(&Bs[q][tx * 4]);
      c[0][0] += a.x * b.x; c[0][1] += a.x * b.y; c[0][2] += a.x * b.z; c[0][3] += a.x * b.w;
      c[1][0] += a.y * b.x; c[1][1] += a.y * b.y; c[1][2] += a.y * b.z; c[1][3] += a.y * b.w;
      c[2][0] += a.z * b.x; c[2][1] += a.z * b.y; c[2][2] += a.z * b.z; c[2][3] += a.z * b.w;
      c[3][0] += a.w * b.x; c[3][1] += a.w * b.y; c[3][2] += a.w * b.z; c[3][3] += a.w * b.w;
    }
    __syncthreads();
  }
  #pragma unroll
  for (int i = 0; i < 4; ++i) {
    *reinterpret_cast<float4*>(
        &Ppart[(size_t)z * 524288u + (m0 + ty * 4 + i) * DIMD + e0 + tx * 4]) =
        make_float4(c[i][0], c[i][1], c[i][2], c[i][3]);
  }
}

// K1c: P = sum over splits; blocks 0,1 also compute
// constv[e] = pw_b[e] + sum_d pw_w[e,d]*dw_b[d]
__global__ __launch_bounds__(256) void k_pcomb(
    const float* __restrict__ Ppart, float* __restrict__ P,
    const float* __restrict__ pw_w, const float* __restrict__ pw_b,
    const float* __restrict__ dw_b, float* __restrict__ constv) {
  const int idx = blockIdx.x * 256 + threadIdx.x;  // over 131072 float4
  const float4* p4 = reinterpret_cast<const float4*>(Ppart);
  float4 a = p4[idx];
  #pragma unroll
  for (int zz = 1; zz < SPLITS; ++zz) {
    float4 v = p4[(size_t)zz * 131072u + idx];
    a.x += v.x; a.y += v.y; a.z += v.z; a.w += v.w;
  }
  reinterpret_cast<float4*>(P)[idx] = a;
  if (blockIdx.x < 2) {
    const int e = blockIdx.x * 256 + threadIdx.x;
    float acc = pw_b[e];
    const float4* pr = reinterpret_cast<const float4*>(&pw_w[e * DIMD]);
    const float4* db = reinterpret_cast<const float4*>(dw_b);
    for (int d4 = 0; d4 < DIMD / 4; ++d4) {
      float4 w = pr[d4]; float4 bb = db[d4];
      acc += w.x * bb.x + w.y * bb.y + w.z * bb.z + w.w * bb.w;
    }
    constv[e] = acc;
  }
}

// ---------------------------------------------------------------------------
// K2: y[b,i,:] = sum_k P[k][x[b,i+k]][:] + constv  (zeros for pad rows)
//     y stored as bf16; fused t[b,i] = dot(y_f32[b,i,:], score_w).
// ---------------------------------------------------------------------------
__global__ __launch_bounds__(128) void k_y(
    const int* __restrict__ x, const float* __restrict__ P,
    const float* __restrict__ constv, const float* __restrict__ score_w,
    unsigned short* __restrict__ y, float* __restrict__ t_out) {
  const int b = blockIdx.y;
  const int i0 = blockIdx.x * 8;
  const int t = threadIdx.x;  // owns 4 elems at e = t*4
  __shared__ float red[2][8];
  float4 cv = reinterpret_cast<const float4*>(constv)[t];
  float4 sw = reinterpret_cast<const float4*>(score_w)[t];
  float td[8];
  for (int r = 0; r < 8; ++r) {
    const int i = i0 + r;
    float ax = 0.f, ay = 0.f, az = 0.f, aw = 0.f;
    if (i < NSEQ) {
      ax = cv.x; ay = cv.y; az = cv.z; aw = cv.w;
      #pragma unroll
      for (int k = 0; k < 4; ++k) {
        const int pos = i + k;
        if (pos < NSEQ) {
          const int tok = x[b * NSEQ + pos];
          const float4 pv = *reinterpret_cast<const float4*>(
              &P[((unsigned)(k << 8) + tok) * DIMD + t * 4]);
          ax += pv.x; ay += pv.y; az += pv.z; aw += pv.w;
        }
      }
    }
    ushort4 o;
    o.x = f2bf(ax); o.y = f2bf(ay); o.z = f2bf(az); o.w = f2bf(aw);
    *reinterpret_cast<ushort4*>(&y[((size_t)(b * LPAD) + i) * DIMD + t * 4]) = o;
    td[r] = ax * sw.x + ay * sw.y + az * sw.z + aw * sw.w;
  }
  const int lane = t & 63, wv = t >> 6;
  #pragma unroll
  for (int r = 0; r < 8; ++r) {
    float p = td[r];
    for (int off = 32; off > 0; off >>= 1) p += __shfl_down(p, off);
    if (lane == 0) red[wv][r] = p;
  }
  __syncthreads();
  if (t < 8) t_out[b * LPAD + i0 + t] = red[0][t] + red[1][t];
}

// ---------------------------------------------------------------------------
// K4: s[b,l,:] = softmax_k( blockmean_k(t) + score_b ); zero-inits Aacc.
// ---------------------------------------------------------------------------
__global__ __launch_bounds__(256) void k_s(
    const float* __restrict__ t_in, const float* __restrict__ score_b_p,
    float* __restrict__ s, float* __restrict__ Aacc) {
  const int b = blockIdx.y;
  const int l = blockIdx.x * 256 + threadIdx.x;
  if (l >= LPAD) return;
  reinterpret_cast<float4*>(Aacc)[(size_t)(b * LPAD) + l] = make_float4(0.f, 0.f, 0.f, 0.f);
  const float* tb = &t_in[b * LPAD];
  const float sb = score_b_p[0];
  float p0 = tb[l] + sb;
  int j2 = l & ~1;
  float p1 = (tb[j2] + tb[j2 + 1]) * 0.5f + sb;
  int j3 = (l / 3) * 3;
  float p2 = (tb[j3] + tb[j3 + 1] + tb[j3 + 2]) * (1.0f / 3.0f) + sb;
  int j4 = l & ~3;
  float p3 = (tb[j4] + tb[j4 + 1] + tb[j4 + 2] + tb[j4 + 3]) * 0.25f + sb;
  float mx = fmaxf(fmaxf(p0, p1), fmaxf(p2, p3));
  float e0 = __expf(p0 - mx), e1 = __expf(p1 - mx);
  float e2 = __expf(p2 - mx), e3 = __expf(p3 - mx);
  float inv = 1.0f / (e0 + e1 + e2 + e3);
  *reinterpret_cast<float4*>(&s[((size_t)(b * LPAD) + l) * 4]) =
      make_float4(e0 * inv, e1 * inv, e2 * inv, e3 * inv);
}

// ---------------------------------------------------------------------------
// K5: streaming attention over 12 j-chunks; atomic accumulation into Aacc.
// sim in [0,1] => exp never overflows => no max tracking needed.
// Z is NOT accumulated: rows of s sum to 1, so Z_i = sum_k Aacc_ik.
// ---------------------------------------------------------------------------
__global__ __launch_bounds__(256) void k_attn(
    const float* __restrict__ s, float* __restrict__ Aacc) {
  const int b = blockIdx.z;
  const int c = blockIdx.y;
  const int i = blockIdx.x * 256 + threadIdx.x;
  __shared__ float4 sch[CH];
  const float4* s4 = reinterpret_cast<const float4*>(s) + (size_t)b * LPAD;
  const int j0 = c * CH;
  for (int idx = threadIdx.x; idx < CH; idx += 256) sch[idx] = s4[j0 + idx];
  __syncthreads();
  if (i >= LPAD) return;
  float4 si = s4[i];
  float a0x = 0.f, a0y = 0.f, a0z = 0.f, a0w = 0.f;
  float a1x = 0.f, a1y = 0.f, a1z = 0.f, a1w = 0.f;
  #pragma unroll 3
  for (int jj = 0; jj < CH; jj += 2) {
    float4 u = sch[jj];
    float4 v = sch[jj + 1];
    float d0 = si.x * u.x + si.y * u.y + si.z * u.z + si.w * u.w;
    float d1 = si.x * v.x + si.y * v.y + si.z * v.z + si.w * v.w;
    float e0 = __expf(d0), e1 = __expf(d1);
    a0x += e0 * u.x; a0y += e0 * u.y; a0z += e0 * u.z; a0w += e0 * u.w;
    a1x += e1 * v.x; a1y += e1 * v.y; a1z += e1 * v.z; a1w += e1 * v.w;
  }
  float* aa = &Aacc[((size_t)(b * LPAD) + i) * 4];
  atomicAdd(aa + 0, a0x + a1x);
  atomicAdd(aa + 1, a0y + a1y);
  atomicAdd(aa + 2, a0z + a1z);
  atomicAdd(aa + 3, a0w + a1w);
}

// ---------------------------------------------------------------------------
// K7: final recombine + DS-mean; s2 computed inline from Aacc.
// 2 output groups per 256-thread block.
// out[b,g,:] = sum_{r<8} coef[r]*y[b,jbase+r,:]
// ---------------------------------------------------------------------------
__global__ __launch_bounds__(256) void k_out(
    const unsigned short* __restrict__ y, const float* __restrict__ Aacc,
    float* __restrict__ out) {
  const int b = blockIdx.y;
  const int h = threadIdx.x >> 7;          // 0,1: which group half
  const int tl = threadIdx.x & 127;
  const int g = blockIdx.x * 2 + h;
  __shared__ float coef[2][8];
  const int jbase = (g == 0) ? 0 : 4 * g - 2;
  if (tl == 0) {
    float cf[8] = {0.f, 0.f, 0.f, 0.f, 0.f, 0.f, 0.f, 0.f};
    const float4* a4 = reinterpret_cast<const float4*>(Aacc) + (size_t)b * LPAD;
    for (int dl = 0; dl < 4; ++dl) {
      int l = 4 * g + dl;
      float4 av = a4[l];
      float inv = 1.0f / (av.x + av.y + av.z + av.w);
      float sk[4] = {av.x * inv, av.y * inv, av.z * inv, av.w * inv};
      for (int k = 0; k < 4; ++k) {
        int bs = k + 1;
        int j0 = (l / bs) * bs;
        float wv = sk[k] / (float)(bs * 4);
        for (int jj = 0; jj < bs; ++jj) cf[j0 + jj - jbase] += wv;
      }
    }
    for (int r = 0; r < 8; ++r) coef[h][r] = cf[r];
  }
  __syncthreads();
  const unsigned short* yb = y + ((size_t)(b * LPAD) + jbase) * DIMD + tl * 4;
  float ax = 0.f, ay = 0.f, az = 0.f, aw = 0.f;
  #pragma unroll
  for (int r = 0; r < 8; ++r) {
    float cr = coef[h][r];
    ushort4 v = *reinterpret_cast<const ushort4*>(&yb[r * DIMD]);
    ax += cr * bf2f(v.x); ay += cr * bf2f(v.y);
    az += cr * bf2f(v.z); aw += cr * bf2f(v.w);
  }
  reinterpret_cast<float4*>(out)[((size_t)(b * 1024) + g) * 128 + tl] =
      make_float4(ax, ay, az, aw);
}

extern "C" void kernel_launch(void* const* d_in, const int* in_sizes, int n_in,
                              void* d_out, int out_size, void* d_ws, size_t ws_size,
                              hipStream_t stream) {
  const int* x = (const int*)d_in[0];
  const float* emb = (const float*)d_in[1];
  const float* dw_w = (const float*)d_in[2];
  const float* dw_b = (const float*)d_in[3];
  const float* pw_w = (const float*)d_in[4];
  const float* pw_b = (const float*)d_in[5];
  const float* score_w = (const float*)d_in[6];
  const float* score_b = (const float*)d_in[7];
  float* out = (float*)d_out;
  float* ws = (float*)d_ws;
  float* P      = ws + OFF_P;
  float* constv = ws + OFF_CONST;
  float* t      = ws + OFF_T;
  float* s      = ws + OFF_S;
  float* Aacc   = ws + OFF_AACC;
  unsigned short* y = (unsigned short*)(ws + OFF_Y);
  float* Ppart  = ws + OFF_PPART;

  k_ptable<<<dim3(16, 8, SPLITS), 256, 0, stream>>>(emb, dw_w, pw_w, Ppart);
  k_pcomb<<<512, 256, 0, stream>>>(Ppart, P, pw_w, pw_b, dw_b, constv);
  k_y<<<dim3(513, 4), 128, 0, stream>>>(x, P, constv, score_w, y, t);
  k_s<<<dim3(17, 4), 256, 0, stream>>>(t, score_b, s, Aacc);
  k_attn<<<dim3(17, NCH, 4), 256, 0, stream>>>(s, Aacc);
  k_out<<<dim3(512, 4), 256, 0, stream>>>(y, Aacc, out);
}

// Round 5
// 152.147 us; speedup vs baseline: 1.3687x; 1.0271x over previous
//
#include <hip/hip_runtime.h>
#include <hip/hip_bf16.h>

#define DIMD 512
#define NSEQ 4096
#define LPAD 4104
#define NCH 12
#define CH 342          // 12 * 342 = 4104 exactly
#define SPLITS 8
#define PT_BK 32

// ws layout (float offsets) — total 4,851,456 floats = 19.4 MB.
#define OFF_P      0u          // 4*256*512 = 524288
#define OFF_CONST  524288u     // 512
#define OFF_Q      524800u     // 4*256 = 1024
#define OFF_S      525824u     // 4*4104*4 = 65664
#define OFF_AACC   591488u     // 4*4104*4 = 65664
#define OFF_PPART  657152u     // 8*1024*512 = 4194304

// ---------------------------------------------------------------------------
// K1: split-K GEMM for P[k*256+v][e] = sum_d emb[v,d]*dw_w[d,k]*pw_w[e,d]
// M=1024 (k,v), N=512 (e), K=512 (d). 64x64 tiles, 8 K-splits of 64, BK=32.
// ---------------------------------------------------------------------------
__global__ __launch_bounds__(256) void k_ptable(
    const float* __restrict__ emb, const float* __restrict__ dw_w,
    const float* __restrict__ pw_w, float* __restrict__ Ppart) {
  __shared__ float As[PT_BK][68];   // [d_local][m_row]
  __shared__ float Bs[PT_BK][68];   // [d_local][e_row]
  const int tid = threadIdx.x;
  const int m0 = blockIdx.x * 64;
  const int e0 = blockIdx.y * 64;
  const int z  = blockIdx.z;
  const int kk = m0 >> 8;           // conv tap, constant per block
  const int v0 = m0 & 255;
  const int srow = tid >> 3;        // 0..31
  const int sd4  = (tid & 7) * 4;   // 0..28
  const int ty = tid >> 4, tx = tid & 15;
  float c[4][4] = {};
  for (int kt = 0; kt < 64; kt += PT_BK) {
    const int d0 = z * 64 + kt;
    const float dw0 = dw_w[(d0 + sd4 + 0) * 4 + kk];
    const float dw1 = dw_w[(d0 + sd4 + 1) * 4 + kk];
    const float dw2 = dw_w[(d0 + sd4 + 2) * 4 + kk];
    const float dw3 = dw_w[(d0 + sd4 + 3) * 4 + kk];
    #pragma unroll
    for (int rr = 0; rr < 2; ++rr) {
      const int row = srow + rr * 32;
      float4 ev = *reinterpret_cast<const float4*>(&emb[(v0 + row) * DIMD + d0 + sd4]);
      As[sd4 + 0][row] = ev.x * dw0;
      As[sd4 + 1][row] = ev.y * dw1;
      As[sd4 + 2][row] = ev.z * dw2;
      As[sd4 + 3][row] = ev.w * dw3;
      float4 bv = *reinterpret_cast<const float4*>(&pw_w[(e0 + row) * DIMD + d0 + sd4]);
      Bs[sd4 + 0][row] = bv.x;
      Bs[sd4 + 1][row] = bv.y;
      Bs[sd4 + 2][row] = bv.z;
      Bs[sd4 + 3][row] = bv.w;
    }
    __syncthreads();
    #pragma unroll
    for (int q = 0; q < PT_BK; ++q) {
      float4 a = *reinterpret_cast<const float4*>(&As[q][ty * 4]);
      float4 b = *reinterpret_cast<const float4*>(&Bs[q][tx * 4]);
      c[0][0] += a.x * b.x; c[0][1] += a.x * b.y; c[0][2] += a.x * b.z; c[0][3] += a.x * b.w;
      c[1][0] += a.y * b.x; c[1][1] += a.y * b.y; c[1][2] += a.y * b.z; c[1][3] += a.y * b.w;
      c[2][0] += a.z * b.x; c[2][1] += a.z * b.y; c[2][2] += a.z * b.z; c[2][3] += a.z * b.w;
      c[3][0] += a.w * b.x; c[3][1] += a.w * b.y; c[3][2] += a.w * b.z; c[3][3] += a.w * b.w;
    }
    __syncthreads();
  }
  #pragma unroll
  for (int i = 0; i < 4; ++i) {
    *reinterpret_cast<float4*>(
        &Ppart[(size_t)z * 524288u + (m0 + ty * 4 + i) * DIMD + e0 + tx * 4]) =
        make_float4(c[i][0], c[i][1], c[i][2], c[i][3]);
  }
}

// ---------------------------------------------------------------------------
// K1c: P = sum over splits. Fused extras:
//  - q[row] = dot(P[row,:], score_w)  (per-row wave reduction; row = k*256+v)
//  - blocks 0,1: constv[e] = pw_b[e] + sum_d pw_w[e,d]*dw_b[d]
// ---------------------------------------------------------------------------
__global__ __launch_bounds__(256) void k_pcomb(
    const float* __restrict__ Ppart, float* __restrict__ P,
    const float* __restrict__ pw_w, const float* __restrict__ pw_b,
    const float* __restrict__ dw_b, const float* __restrict__ score_w,
    float* __restrict__ constv, float* __restrict__ q) {
  __shared__ float qred[4];
  const int tid = threadIdx.x;
  const int idx = blockIdx.x * 256 + tid;  // over 131072 float4; 2 rows/block
  const float4* p4 = reinterpret_cast<const float4*>(Ppart);
  float4 a = p4[idx];
  #pragma unroll
  for (int zz = 1; zz < SPLITS; ++zz) {
    float4 v = p4[(size_t)zz * 131072u + idx];
    a.x += v.x; a.y += v.y; a.z += v.z; a.w += v.w;
  }
  reinterpret_cast<float4*>(P)[idx] = a;
  // q partial: this thread covers e = (idx&127)*4 .. +3 of row idx>>7
  float4 sw = reinterpret_cast<const float4*>(score_w)[idx & 127];
  float part = a.x * sw.x + a.y * sw.y + a.z * sw.z + a.w * sw.w;
  for (int off = 32; off > 0; off >>= 1) part += __shfl_down(part, off);
  if ((tid & 63) == 0) qred[tid >> 6] = part;
  __syncthreads();
  if (tid == 0)   q[blockIdx.x * 2 + 0] = qred[0] + qred[1];
  if (tid == 128) q[blockIdx.x * 2 + 1] = qred[2] + qred[3];
  if (blockIdx.x < 2) {
    const int e = blockIdx.x * 256 + tid;
    float acc = pw_b[e];
    const float4* pr = reinterpret_cast<const float4*>(&pw_w[e * DIMD]);
    const float4* db = reinterpret_cast<const float4*>(dw_b);
    for (int d4 = 0; d4 < DIMD / 4; ++d4) {
      float4 w = pr[d4]; float4 bb = db[d4];
      acc += w.x * bb.x + w.y * bb.y + w.z * bb.z + w.w * bb.w;
    }
    constv[e] = acc;
  }
}

// ---------------------------------------------------------------------------
// K2: fused t -> blockmean -> softmax -> s; zero-inits Aacc.
// t[l] = c0 + sum_k q[k][x[l+k]]  (0 for pad rows), computed in LDS with
// halo [l0-2, l0+258]; c0 = dot(constv, score_w) reduced per block (cheap).
// ---------------------------------------------------------------------------
__global__ __launch_bounds__(256) void k_scores(
    const int* __restrict__ x, const float* __restrict__ q,
    const float* __restrict__ constv, const float* __restrict__ score_w,
    const float* __restrict__ score_b_p, float* __restrict__ s,
    float* __restrict__ Aacc) {
  __shared__ float qlds[1024];
  __shared__ float tlds[264];
  __shared__ float c0red[2];
  const int b = blockIdx.y;
  const int l0 = blockIdx.x * 256;
  const int tid = threadIdx.x;
  reinterpret_cast<float4*>(qlds)[tid] = reinterpret_cast<const float4*>(q)[tid];
  if (tid < 128) {
    float4 cv = reinterpret_cast<const float4*>(constv)[tid];
    float4 sw = reinterpret_cast<const float4*>(score_w)[tid];
    float part = cv.x * sw.x + cv.y * sw.y + cv.z * sw.z + cv.w * sw.w;
    for (int off = 32; off > 0; off >>= 1) part += __shfl_down(part, off);
    if ((tid & 63) == 0) c0red[tid >> 6] = part;
  }
  __syncthreads();
  const float c0 = c0red[0] + c0red[1];
  const int* xb = &x[b * NSEQ];
  auto tval = [&](int l) -> float {
    if ((unsigned)l >= (unsigned)NSEQ) return 0.f;
    float acc = c0;
    #pragma unroll
    for (int k = 0; k < 4; ++k) {
      const int pos = l + k;
      if (pos < NSEQ) acc += qlds[(k << 8) + xb[pos]];
    }
    return acc;
  };
  tlds[tid] = tval(l0 - 2 + tid);
  if (tid < 5) tlds[256 + tid] = tval(l0 + 254 + tid);
  __syncthreads();
  const int l = l0 + tid;
  if (l >= LPAD) return;
  reinterpret_cast<float4*>(Aacc)[(size_t)(b * LPAD) + l] = make_float4(0.f, 0.f, 0.f, 0.f);
  const float sb = score_b_p[0];
  #define TT(j) tlds[(j) - l0 + 2]
  float p0 = TT(l) + sb;
  int j2 = l & ~1;
  float p1 = (TT(j2) + TT(j2 + 1)) * 0.5f + sb;
  int j3 = (l / 3) * 3;
  float p2 = (TT(j3) + TT(j3 + 1) + TT(j3 + 2)) * (1.0f / 3.0f) + sb;
  int j4 = l & ~3;
  float p3 = (TT(j4) + TT(j4 + 1) + TT(j4 + 2) + TT(j4 + 3)) * 0.25f + sb;
  #undef TT
  float mx = fmaxf(fmaxf(p0, p1), fmaxf(p2, p3));
  float e0 = __expf(p0 - mx), e1 = __expf(p1 - mx);
  float e2 = __expf(p2 - mx), e3 = __expf(p3 - mx);
  float inv = 1.0f / (e0 + e1 + e2 + e3);
  *reinterpret_cast<float4*>(&s[((size_t)(b * LPAD) + l) * 4]) =
      make_float4(e0 * inv, e1 * inv, e2 * inv, e3 * inv);
}

// ---------------------------------------------------------------------------
// K5: streaming attention over 12 j-chunks; atomic accumulation into Aacc.
// sim in [0,1] => exp never overflows => no max tracking needed.
// Z not accumulated: rows of s sum to 1, so Z_i = sum_k Aacc_ik.
// ---------------------------------------------------------------------------
__global__ __launch_bounds__(256) void k_attn(
    const float* __restrict__ s, float* __restrict__ Aacc) {
  const int b = blockIdx.z;
  const int c = blockIdx.y;
  const int i = blockIdx.x * 256 + threadIdx.x;
  __shared__ float4 sch[CH];
  const float4* s4 = reinterpret_cast<const float4*>(s) + (size_t)b * LPAD;
  float4 si = s4[i < LPAD ? i : 0];
  const int j0 = c * CH;
  for (int idx = threadIdx.x; idx < CH; idx += 256) sch[idx] = s4[j0 + idx];
  __syncthreads();
  if (i >= LPAD) return;
  float a0x = 0.f, a0y = 0.f, a0z = 0.f, a0w = 0.f;
  float a1x = 0.f, a1y = 0.f, a1z = 0.f, a1w = 0.f;
  #pragma unroll 3
  for (int jj = 0; jj < CH; jj += 2) {
    float4 u = sch[jj];
    float4 v = sch[jj + 1];
    float d0 = si.x * u.x + si.y * u.y + si.z * u.z + si.w * u.w;
    float d1 = si.x * v.x + si.y * v.y + si.z * v.z + si.w * v.w;
    float e0 = __expf(d0), e1 = __expf(d1);
    a0x += e0 * u.x; a0y += e0 * u.y; a0z += e0 * u.z; a0w += e0 * u.w;
    a1x += e1 * v.x; a1y += e1 * v.y; a1z += e1 * v.z; a1w += e1 * v.w;
  }
  float* aa = &Aacc[((size_t)(b * LPAD) + i) * 4];
  atomicAdd(aa + 0, a0x + a1x);
  atomicAdd(aa + 1, a0y + a1y);
  atomicAdd(aa + 2, a0z + a1z);
  atomicAdd(aa + 3, a0w + a1w);
}

// ---------------------------------------------------------------------------
// K7: final recombine + DS-mean, with y recomputed from the P gather
// (y never materialized). out[b,g,:] = sum_{r<8} coef[r]*y[b,jbase+r,:]
//   = (sum coef)*const + sum_{r,k} coef[r]*P[k][x[row+k]][:]
// s2 computed inline from Aacc. 2 groups per 256-thread block.
// ---------------------------------------------------------------------------
__global__ __launch_bounds__(256) void k_out(
    const int* __restrict__ x, const float* __restrict__ P,
    const float* __restrict__ constv, const float* __restrict__ Aacc,
    float* __restrict__ out) {
  const int b = blockIdx.y;
  const int h = threadIdx.x >> 7;
  const int tl = threadIdx.x & 127;
  const int g = blockIdx.x * 2 + h;
  __shared__ float coef[2][8];
  const int jbase = (g == 0) ? 0 : 4 * g - 2;
  if (tl == 0) {
    float cf[8] = {0.f, 0.f, 0.f, 0.f, 0.f, 0.f, 0.f, 0.f};
    const float4* a4 = reinterpret_cast<const float4*>(Aacc) + (size_t)b * LPAD;
    for (int dl = 0; dl < 4; ++dl) {
      int l = 4 * g + dl;
      float4 av = a4[l];
      float inv = 1.0f / (av.x + av.y + av.z + av.w);
      float sk[4] = {av.x * inv, av.y * inv, av.z * inv, av.w * inv};
      for (int k = 0; k < 4; ++k) {
        int bs = k + 1;
        int j0 = (l / bs) * bs;
        float wv = sk[k] / (float)(bs * 4);
        for (int jj = 0; jj < bs; ++jj) cf[j0 + jj - jbase] += wv;
      }
    }
    for (int r = 0; r < 8; ++r) coef[h][r] = cf[r];
  }
  __syncthreads();
  const int* xb = &x[b * NSEQ];
  float ax = 0.f, ay = 0.f, az = 0.f, aw = 0.f;
  float csum = 0.f;
  #pragma unroll
  for (int r = 0; r < 8; ++r) {
    const int row = jbase + r;
    if (row < NSEQ) {
      const float cr = coef[h][r];
      csum += cr;
      #pragma unroll
      for (int k = 0; k < 4; ++k) {
        const int pos = row + k;
        if (pos < NSEQ) {
          const int tok = xb[pos];
          const float4 pv = *reinterpret_cast<const float4*>(
              &P[((unsigned)(k << 8) + tok) * DIMD + tl * 4]);
          ax += cr * pv.x; ay += cr * pv.y; az += cr * pv.z; aw += cr * pv.w;
        }
      }
    }
  }
  const float4 cv = reinterpret_cast<const float4*>(constv)[tl];
  ax += csum * cv.x; ay += csum * cv.y; az += csum * cv.z; aw += csum * cv.w;
  reinterpret_cast<float4*>(out)[((size_t)(b * 1024) + g) * 128 + tl] =
      make_float4(ax, ay, az, aw);
}

extern "C" void kernel_launch(void* const* d_in, const int* in_sizes, int n_in,
                              void* d_out, int out_size, void* d_ws, size_t ws_size,
                              hipStream_t stream) {
  const int* x = (const int*)d_in[0];
  const float* emb = (const float*)d_in[1];
  const float* dw_w = (const float*)d_in[2];
  const float* dw_b = (const float*)d_in[3];
  const float* pw_w = (const float*)d_in[4];
  const float* pw_b = (const float*)d_in[5];
  const float* score_w = (const float*)d_in[6];
  const float* score_b = (const float*)d_in[7];
  float* out = (float*)d_out;
  float* ws = (float*)d_ws;
  float* P      = ws + OFF_P;
  float* constv = ws + OFF_CONST;
  float* q      = ws + OFF_Q;
  float* s      = ws + OFF_S;
  float* Aacc   = ws + OFF_AACC;
  float* Ppart  = ws + OFF_PPART;

  k_ptable<<<dim3(16, 8, SPLITS), 256, 0, stream>>>(emb, dw_w, pw_w, Ppart);
  k_pcomb<<<512, 256, 0, stream>>>(Ppart, P, pw_w, pw_b, dw_b, score_w, constv, q);
  k_scores<<<dim3(17, 4), 256, 0, stream>>>(x, q, constv, score_w, score_b, s, Aacc);
  k_attn<<<dim3(17, NCH, 4), 256, 0, stream>>>(s, Aacc);
  k_out<<<dim3(512, 4), 256, 0, stream>>>(x, P, constv, Aacc, out);
}

// Round 6
// 149.272 us; speedup vs baseline: 1.3950x; 1.0193x over previous
//
#include <hip/hip_runtime.h>
#include <hip/hip_bf16.h>

#define DIMD 512
#define NSEQ 4096
#define LPAD 4104
#define NCH 12
#define CH 342          // 12 * 342 = 4104 exactly
#define SPLITS 8
#define PT_BK 32

// ws layout (float offsets) — total 4,785,792 floats = 19.1 MB.
#define OFF_P      0u          // 4*256*512 = 524288
#define OFF_CONST  524288u     // 512
#define OFF_Q      524800u     // 4*256 = 1024
#define OFF_AACC   525824u     // 4*4104*4 = 65664
#define OFF_PPART  591488u     // 8*1024*512 = 4194304

// ---------------------------------------------------------------------------
// K1: split-K GEMM for P[k*256+v][e] = sum_d emb[v,d]*dw_w[d,k]*pw_w[e,d]
// M=1024 (k,v), N=512 (e), K=512 (d). 64x64 tiles, 8 K-splits of 64, BK=32.
// ---------------------------------------------------------------------------
__global__ __launch_bounds__(256) void k_ptable(
    const float* __restrict__ emb, const float* __restrict__ dw_w,
    const float* __restrict__ pw_w, float* __restrict__ Ppart) {
  __shared__ float As[PT_BK][68];   // [d_local][m_row]
  __shared__ float Bs[PT_BK][68];   // [d_local][e_row]
  const int tid = threadIdx.x;
  const int m0 = blockIdx.x * 64;
  const int e0 = blockIdx.y * 64;
  const int z  = blockIdx.z;
  const int kk = m0 >> 8;           // conv tap, constant per block
  const int v0 = m0 & 255;
  const int srow = tid >> 3;        // 0..31
  const int sd4  = (tid & 7) * 4;   // 0..28
  const int ty = tid >> 4, tx = tid & 15;
  float c[4][4] = {};
  for (int kt = 0; kt < 64; kt += PT_BK) {
    const int d0 = z * 64 + kt;
    const float dw0 = dw_w[(d0 + sd4 + 0) * 4 + kk];
    const float dw1 = dw_w[(d0 + sd4 + 1) * 4 + kk];
    const float dw2 = dw_w[(d0 + sd4 + 2) * 4 + kk];
    const float dw3 = dw_w[(d0 + sd4 + 3) * 4 + kk];
    #pragma unroll
    for (int rr = 0; rr < 2; ++rr) {
      const int row = srow + rr * 32;
      float4 ev = *reinterpret_cast<const float4*>(&emb[(v0 + row) * DIMD + d0 + sd4]);
      As[sd4 + 0][row] = ev.x * dw0;
      As[sd4 + 1][row] = ev.y * dw1;
      As[sd4 + 2][row] = ev.z * dw2;
      As[sd4 + 3][row] = ev.w * dw3;
      float4 bv = *reinterpret_cast<const float4*>(&pw_w[(e0 + row) * DIMD + d0 + sd4]);
      Bs[sd4 + 0][row] = bv.x;
      Bs[sd4 + 1][row] = bv.y;
      Bs[sd4 + 2][row] = bv.z;
      Bs[sd4 + 3][row] = bv.w;
    }
    __syncthreads();
    #pragma unroll
    for (int q = 0; q < PT_BK; ++q) {
      float4 a = *reinterpret_cast<const float4*>(&As[q][ty * 4]);
      float4 b = *reinterpret_cast<const float4*>(&Bs[q][tx * 4]);
      c[0][0] += a.x * b.x; c[0][1] += a.x * b.y; c[0][2] += a.x * b.z; c[0][3] += a.x * b.w;
      c[1][0] += a.y * b.x; c[1][1] += a.y * b.y; c[1][2] += a.y * b.z; c[1][3] += a.y * b.w;
      c[2][0] += a.z * b.x; c[2][1] += a.z * b.y; c[2][2] += a.z * b.z; c[2][3] += a.z * b.w;
      c[3][0] += a.w * b.x; c[3][1] += a.w * b.y; c[3][2] += a.w * b.z; c[3][3] += a.w * b.w;
    }
    __syncthreads();
  }
  #pragma unroll
  for (int i = 0; i < 4; ++i) {
    *reinterpret_cast<float4*>(
        &Ppart[(size_t)z * 524288u + (m0 + ty * 4 + i) * DIMD + e0 + tx * 4]) =
        make_float4(c[i][0], c[i][1], c[i][2], c[i][3]);
  }
}

// ---------------------------------------------------------------------------
// K1c: P = sum over splits. Fused extras:
//  - q[row] = dot(P[row,:], score_w)  (per-row wave reduction; row = k*256+v)
//  - blocks 0,1: constv[e] = pw_b[e] + sum_d pw_w[e,d]*dw_b[d]
// ---------------------------------------------------------------------------
__global__ __launch_bounds__(256) void k_pcomb(
    const float* __restrict__ Ppart, float* __restrict__ P,
    const float* __restrict__ pw_w, const float* __restrict__ pw_b,
    const float* __restrict__ dw_b, const float* __restrict__ score_w,
    float* __restrict__ constv, float* __restrict__ q) {
  __shared__ float qred[4];
  const int tid = threadIdx.x;
  const int idx = blockIdx.x * 256 + tid;  // over 131072 float4; 2 rows/block
  const float4* p4 = reinterpret_cast<const float4*>(Ppart);
  float4 a = p4[idx];
  #pragma unroll
  for (int zz = 1; zz < SPLITS; ++zz) {
    float4 v = p4[(size_t)zz * 131072u + idx];
    a.x += v.x; a.y += v.y; a.z += v.z; a.w += v.w;
  }
  reinterpret_cast<float4*>(P)[idx] = a;
  float4 sw = reinterpret_cast<const float4*>(score_w)[idx & 127];
  float part = a.x * sw.x + a.y * sw.y + a.z * sw.z + a.w * sw.w;
  for (int off = 32; off > 0; off >>= 1) part += __shfl_down(part, off);
  if ((tid & 63) == 0) qred[tid >> 6] = part;
  __syncthreads();
  if (tid == 0)   q[blockIdx.x * 2 + 0] = qred[0] + qred[1];
  if (tid == 128) q[blockIdx.x * 2 + 1] = qred[2] + qred[3];
  if (blockIdx.x < 2) {
    const int e = blockIdx.x * 256 + tid;
    float acc = pw_b[e];
    const float4* pr = reinterpret_cast<const float4*>(&pw_w[e * DIMD]);
    const float4* db = reinterpret_cast<const float4*>(dw_b);
    for (int d4 = 0; d4 < DIMD / 4; ++d4) {
      float4 w = pr[d4]; float4 bb = db[d4];
      acc += w.x * bb.x + w.y * bb.y + w.z * bb.z + w.w * bb.w;
    }
    constv[e] = acc;
  }
}

// ---------------------------------------------------------------------------
// K5: streaming attention with s computed INLINE (k_scores eliminated).
// Per block: rebuild t (from q-table) and s for its 256 i-rows and its
// 342-row j-chunk, entirely in LDS; then the usual exp(si.sj) accumulation
// with atomics into Aacc. sim in [0,1] => no max tracking needed.
// Z not accumulated: rows of s sum to 1, so Z_i = sum_k Aacc_ik.
// ---------------------------------------------------------------------------
__global__ __launch_bounds__(256) void k_attn(
    const int* __restrict__ x, const float* __restrict__ q,
    const float* __restrict__ constv, const float* __restrict__ score_w,
    const float* __restrict__ score_b_p, float* __restrict__ Aacc) {
  __shared__ float qlds[1024];
  __shared__ float tli[264];   // t for [i0-2, i0+258]
  __shared__ float tlj[348];   // t for [j0-2, j0+344]
  __shared__ float4 sch[CH];
  __shared__ float c0red[2];
  const int b = blockIdx.z;
  const int c = blockIdx.y;
  const int i0 = blockIdx.x * 256;
  const int j0 = c * CH;
  const int tid = threadIdx.x;
  reinterpret_cast<float4*>(qlds)[tid] = reinterpret_cast<const float4*>(q)[tid];
  if (tid < 128) {
    float4 cv = reinterpret_cast<const float4*>(constv)[tid];
    float4 sw = reinterpret_cast<const float4*>(score_w)[tid];
    float part = cv.x * sw.x + cv.y * sw.y + cv.z * sw.z + cv.w * sw.w;
    for (int off = 32; off > 0; off >>= 1) part += __shfl_down(part, off);
    if ((tid & 63) == 0) c0red[tid >> 6] = part;
  }
  __syncthreads();
  const float c0 = c0red[0] + c0red[1];
  const int* xb = &x[b * NSEQ];
  auto tval = [&](int l) -> float {
    if ((unsigned)l >= (unsigned)NSEQ) return 0.f;
    float acc = c0;
    #pragma unroll
    for (int k = 0; k < 4; ++k) {
      const int pos = l + k;
      if (pos < NSEQ) acc += qlds[(k << 8) + xb[pos]];
    }
    return acc;
  };
  for (int idx = tid; idx < 261; idx += 256) tli[idx] = tval(i0 - 2 + idx);
  for (int idx = tid; idx < 347; idx += 256) tlj[idx] = tval(j0 - 2 + idx);
  __syncthreads();
  const float sb = score_b_p[0];
  for (int idx = tid; idx < CH; idx += 256) {
    const int l = j0 + idx;
    #define TJ(j) tlj[(j) - j0 + 2]
    float p0 = TJ(l) + sb;
    int j2 = l & ~1;
    float p1 = (TJ(j2) + TJ(j2 + 1)) * 0.5f + sb;
    int j3 = (l / 3) * 3;
    float p2 = (TJ(j3) + TJ(j3 + 1) + TJ(j3 + 2)) * (1.0f / 3.0f) + sb;
    int j4 = l & ~3;
    float p3 = (TJ(j4) + TJ(j4 + 1) + TJ(j4 + 2) + TJ(j4 + 3)) * 0.25f + sb;
    #undef TJ
    float mx = fmaxf(fmaxf(p0, p1), fmaxf(p2, p3));
    float e0 = __expf(p0 - mx), e1 = __expf(p1 - mx);
    float e2 = __expf(p2 - mx), e3 = __expf(p3 - mx);
    float inv = 1.0f / (e0 + e1 + e2 + e3);
    sch[idx] = make_float4(e0 * inv, e1 * inv, e2 * inv, e3 * inv);
  }
  const int i = i0 + tid;
  float4 si;
  {
    const int l = i;
    #define TI(j) tli[(j) - i0 + 2]
    float p0 = TI(l) + sb;
    int j2 = l & ~1;
    float p1 = (TI(j2) + TI(j2 + 1)) * 0.5f + sb;
    int j3 = (l / 3) * 3;
    float p2 = (TI(j3) + TI(j3 + 1) + TI(j3 + 2)) * (1.0f / 3.0f) + sb;
    int j4 = l & ~3;
    float p3 = (TI(j4) + TI(j4 + 1) + TI(j4 + 2) + TI(j4 + 3)) * 0.25f + sb;
    #undef TI
    float mx = fmaxf(fmaxf(p0, p1), fmaxf(p2, p3));
    float e0 = __expf(p0 - mx), e1 = __expf(p1 - mx);
    float e2 = __expf(p2 - mx), e3 = __expf(p3 - mx);
    float inv = 1.0f / (e0 + e1 + e2 + e3);
    si = make_float4(e0 * inv, e1 * inv, e2 * inv, e3 * inv);
  }
  __syncthreads();
  if (i >= LPAD) return;
  float a0x = 0.f, a0y = 0.f, a0z = 0.f, a0w = 0.f;
  float a1x = 0.f, a1y = 0.f, a1z = 0.f, a1w = 0.f;
  #pragma unroll 3
  for (int jj = 0; jj < CH; jj += 2) {
    float4 u = sch[jj];
    float4 v = sch[jj + 1];
    float d0 = si.x * u.x + si.y * u.y + si.z * u.z + si.w * u.w;
    float d1 = si.x * v.x + si.y * v.y + si.z * v.z + si.w * v.w;
    float e0 = __expf(d0), e1 = __expf(d1);
    a0x += e0 * u.x; a0y += e0 * u.y; a0z += e0 * u.z; a0w += e0 * u.w;
    a1x += e1 * v.x; a1y += e1 * v.y; a1z += e1 * v.z; a1w += e1 * v.w;
  }
  float* aa = &Aacc[((size_t)(b * LPAD) + i) * 4];
  atomicAdd(aa + 0, a0x + a1x);
  atomicAdd(aa + 1, a0y + a1y);
  atomicAdd(aa + 2, a0z + a1z);
  atomicAdd(aa + 3, a0w + a1w);
}

// ---------------------------------------------------------------------------
// K7: final recombine + DS-mean, y recomputed from the P gather.
// 4 groups per 128-thread block; the 4 groups' 8-row bands overlap, so the
// block touches only 20 distinct rows (vs 32) -> 37% less gather traffic.
// coef[g][r] indexed by absolute row - R0, R0 = 4*g0-2.
// ---------------------------------------------------------------------------
__global__ __launch_bounds__(128) void k_out(
    const int* __restrict__ x, const float* __restrict__ P,
    const float* __restrict__ constv, const float* __restrict__ Aacc,
    float* __restrict__ out) {
  const int b = blockIdx.y;
  const int g0 = blockIdx.x * 4;
  const int tl = threadIdx.x;
  const int R0 = 4 * g0 - 2;
  __shared__ float coef[4][20];
  if (tl < 80) (&coef[0][0])[tl] = 0.f;
  __syncthreads();
  if (tl < 4) {
    const int g = g0 + tl;
    const float4* a4 = reinterpret_cast<const float4*>(Aacc) + (size_t)b * LPAD;
    for (int dl = 0; dl < 4; ++dl) {
      const int l = 4 * g + dl;
      float4 av = a4[l];
      float inv = 1.0f / (av.x + av.y + av.z + av.w);
      float sk[4] = {av.x * inv, av.y * inv, av.z * inv, av.w * inv};
      for (int k = 0; k < 4; ++k) {
        const int bs = k + 1;
        const int j0 = (l / bs) * bs;
        const float wv = sk[k] / (float)(bs * 4);
        for (int jj = 0; jj < bs; ++jj) coef[tl][j0 + jj - R0] += wv;
      }
    }
  }
  __syncthreads();
  const int* xb = &x[b * NSEQ];
  const float4 cv = reinterpret_cast<const float4*>(constv)[tl];
  float4 acc0 = {0.f, 0.f, 0.f, 0.f}, acc1 = {0.f, 0.f, 0.f, 0.f};
  float4 acc2 = {0.f, 0.f, 0.f, 0.f}, acc3 = {0.f, 0.f, 0.f, 0.f};
  for (int r = 0; r < 20; ++r) {
    const int row = R0 + r;
    if ((unsigned)row >= (unsigned)NSEQ) continue;   // pad rows have y = 0
    const float c0 = coef[0][r], c1 = coef[1][r];
    const float c2 = coef[2][r], c3 = coef[3][r];
    if (c0 + c1 + c2 + c3 == 0.f) continue;
    float yx = cv.x, yy = cv.y, yz = cv.z, yw = cv.w;
    #pragma unroll
    for (int k = 0; k < 4; ++k) {
      const int pos = row + k;
      if (pos < NSEQ) {
        const int tok = xb[pos];
        const float4 pv = *reinterpret_cast<const float4*>(
            &P[((unsigned)(k << 8) + tok) * DIMD + tl * 4]);
        yx += pv.x; yy += pv.y; yz += pv.z; yw += pv.w;
      }
    }
    acc0.x += c0 * yx; acc0.y += c0 * yy; acc0.z += c0 * yz; acc0.w += c0 * yw;
    acc1.x += c1 * yx; acc1.y += c1 * yy; acc1.z += c1 * yz; acc1.w += c1 * yw;
    acc2.x += c2 * yx; acc2.y += c2 * yy; acc2.z += c2 * yz; acc2.w += c2 * yw;
    acc3.x += c3 * yx; acc3.y += c3 * yy; acc3.z += c3 * yz; acc3.w += c3 * yw;
  }
  float4* o = reinterpret_cast<float4*>(out) + ((size_t)(b * 1024) + g0) * 128 + tl;
  o[0 * 128] = acc0;
  o[1 * 128] = acc1;
  o[2 * 128] = acc2;
  o[3 * 128] = acc3;
}

extern "C" void kernel_launch(void* const* d_in, const int* in_sizes, int n_in,
                              void* d_out, int out_size, void* d_ws, size_t ws_size,
                              hipStream_t stream) {
  const int* x = (const int*)d_in[0];
  const float* emb = (const float*)d_in[1];
  const float* dw_w = (const float*)d_in[2];
  const float* dw_b = (const float*)d_in[3];
  const float* pw_w = (const float*)d_in[4];
  const float* pw_b = (const float*)d_in[5];
  const float* score_w = (const float*)d_in[6];
  const float* score_b = (const float*)d_in[7];
  float* out = (float*)d_out;
  float* ws = (float*)d_ws;
  float* P      = ws + OFF_P;
  float* constv = ws + OFF_CONST;
  float* q      = ws + OFF_Q;
  float* Aacc   = ws + OFF_AACC;
  float* Ppart  = ws + OFF_PPART;

  hipMemsetAsync(Aacc, 0, (size_t)4 * LPAD * 4 * sizeof(float), stream);
  k_ptable<<<dim3(16, 8, SPLITS), 256, 0, stream>>>(emb, dw_w, pw_w, Ppart);
  k_pcomb<<<512, 256, 0, stream>>>(Ppart, P, pw_w, pw_b, dw_b, score_w, constv, q);
  k_attn<<<dim3(17, NCH, 4), 256, 0, stream>>>(x, q, constv, score_w, score_b, Aacc);
  k_out<<<dim3(256, 4), 128, 0, stream>>>(x, P, constv, Aacc, out);
}